// Round 21
// baseline (149.429 us; speedup 1.0000x reference)
//
#include <hip/hip_runtime.h>
#include <stdint.h>

// ---------------------------------------------------------------------------
// MultiHeadAttention fused pipeline, fp16 MFMA, fp32 accumulation.
// B=2, N=2048, DIM=1024, H=16, hd=64.
// Q/K are stored in an INTERLEAVED PERMUTED d-layout: position 2m holds d=m,
// position 2m+1 holds d=m+32 (m=0..31). QK^T is invariant since both operands
// use the same permutation. V is stored permuted too and un-permuted inside
// vtrans (its reads are scalar gathers anyway).
// ---------------------------------------------------------------------------

#define BATCH 2
#define SEQ   2048
#define DIM_C 1024
#define NHEAD 16
#define HD    64
#define MTOT  (BATCH * SEQ)      // 4096
#define NQKV  (3 * DIM_C)        // 3072
// 0.125 * log2(e): QK^T lands in log2 domain -> exp2 (single v_exp_f32)
#define QSCALE 0.1803368801111204f

typedef _Float16 h8 __attribute__((ext_vector_type(8)));
typedef _Float16 h4v __attribute__((ext_vector_type(4)));
typedef _Float16 h2v __attribute__((ext_vector_type(2)));
typedef float    f4 __attribute__((ext_vector_type(4)));
typedef unsigned int u4v __attribute__((ext_vector_type(4)));

#if __has_builtin(__builtin_amdgcn_exp2f)
#define EXP2(x) __builtin_amdgcn_exp2f(x)
#else
#define EXP2(x) exp2f(x)
#endif

__device__ __forceinline__ f4 mfma16(h8 a, h8 b, f4 c) {
  return __builtin_amdgcn_mfma_f32_16x16x32_f16(a, b, c, 0, 0, 0);
}

// pack two f32 -> u32 of two f16
__device__ __forceinline__ unsigned pk2(float a, float b) {
  auto t = __builtin_amdgcn_cvt_pkrtz(a, b);
  unsigned u;
  __builtin_memcpy(&u, &t, 4);
  return u;
}

// a' = {a.lo32, b.lo32}; b' = {a.hi32, b.hi32}
__device__ __forceinline__ void swap32(unsigned& a, unsigned& b) {
#if __has_builtin(__builtin_amdgcn_permlane32_swap)
  typedef unsigned u2_ __attribute__((ext_vector_type(2)));
  u2_ r = __builtin_amdgcn_permlane32_swap(a, b, false, false);
  a = r[0]; b = r[1];
#else
  const bool hi = (threadIdx.x & 32) != 0;
  unsigned sa = __shfl_xor(a, 32), sb = __shfl_xor(b, 32);
  unsigned na = hi ? sb : a, nb = hi ? b : sa;
  a = na; b = nb;
#endif
}
__device__ __forceinline__ void swap16(unsigned& a, unsigned& b) {
#if __has_builtin(__builtin_amdgcn_permlane16_swap)
  typedef unsigned u2_ __attribute__((ext_vector_type(2)));
  u2_ r = __builtin_amdgcn_permlane16_swap(a, b, false, false);
  a = r[0]; b = r[1];
#else
  const bool hi = (threadIdx.x & 16) != 0;
  unsigned sa = __shfl_xor(a, 16), sb = __shfl_xor(b, 16);
  unsigned na = hi ? sb : a, nb = hi ? b : sa;
  a = na; b = nb;
#endif
}

// async global->LDS, 16B per lane; LDS dest must be linear in lane order.
__device__ __forceinline__ void gload16(const _Float16* g, _Float16* l) {
  __builtin_amdgcn_global_load_lds(
      (const __attribute__((address_space(1))) void*)g,
      (__attribute__((address_space(3))) void*)l, 16, 0, 0);
}

// ---------------------------------------------------------------------------
// Fused prep: fp32->fp16 for x / w_qkv / w_out (float4 chunks) + RoPE tables.
// ---------------------------------------------------------------------------
#define N4X  1048576                 // 4096*1024/4
#define N4WQ 786432                  // 3072*1024/4
#define N4WO 262144                  // 1024*1024/4
#define CVT_TOT (N4X + N4WQ + N4WO)  // 2097152
__global__ void prep_kernel(const float* __restrict__ x,
                            const float* __restrict__ wq,
                            const float* __restrict__ wo,
                            _Float16* __restrict__ xh,
                            _Float16* __restrict__ wqh,
                            _Float16* __restrict__ woh,
                            float* __restrict__ cosT, float* __restrict__ sinT) {
  int idx = blockIdx.x * blockDim.x + threadIdx.x;   // CVT_TOT + 65536 exact
  if (idx < CVT_TOT) {
    const float* s; _Float16* d; int i;
    if (idx < N4X) { s = x; d = xh; i = idx; }
    else if (idx < N4X + N4WQ) { s = wq; d = wqh; i = idx - N4X; }
    else { s = wo; d = woh; i = idx - (N4X + N4WQ); }
    float4 v = reinterpret_cast<const float4*>(s)[i];
    h4v o = {(_Float16)v.x, (_Float16)v.y, (_Float16)v.z, (_Float16)v.w};
    reinterpret_cast<h4v*>(d)[i] = o;
  } else {
    int t = idx - CVT_TOT;           // 0..65535: SEQ x 32
    int n = t >> 5, j = t & 31;
    float inv = powf(10000.0f, -(float)(2 * j) / 64.0f);
    float a = (float)n * inv;
    cosT[t] = cosf(a);
    sinT[t] = sinf(a);
  }
}

// ---------------------------------------------------------------------------
// QKV GEMM with fused RoPE epilogue. 128x64 tile (one head per block) ->
// 1536 blocks. Wave columns: wb = wave&1 selects {wb*16..+15} U {wb*16+32..+47}
// so the RoPE pair (d, d+32) = (acc[i][0], acc[i][1]) is thread-local.
// Conflict-free LDS + XOR chunk swizzle (both sides). Epilogue: one h2 (4B)
// store per row in the interleaved permuted d-layout.
// ---------------------------------------------------------------------------
__global__ __launch_bounds__(256) void gemm_qkv(const _Float16* __restrict__ A,
                                                const _Float16* __restrict__ Bm,
                                                const float* __restrict__ cosT,
                                                const float* __restrict__ sinT,
                                                _Float16* __restrict__ qh,
                                                _Float16* __restrict__ kh,
                                                _Float16* __restrict__ vh) {
  const int K = DIM_C;
  __shared__ _Float16 Ah[2][64 * 64];
  __shared__ _Float16 Bh[2][32 * 64];
  const int tid = threadIdx.x;
  const int wave = tid >> 6, lane = tid & 63;
  const int lr = lane & 15, lg = lane >> 4;
  const int p = blockIdx.x;             // 0..1535
  const int wg = (p & 7) * 192 + (p >> 3);
  const int bx = wg >> 5, by = wg & 31; // bx 0..47, by 0..31
  const int m0 = by * 128, n0 = bx * 64;
  const int wr = (wave >> 1) * 64, wb = wave & 1;

  const f4 zf = {0.f, 0.f, 0.f, 0.f};
  f4 acc[4][2];
#pragma unroll
  for (int i = 0; i < 4; ++i)
#pragma unroll
    for (int j = 0; j < 2; ++j) acc[i][j] = zf;

  const _Float16* Ab = A + (size_t)m0 * K;
  const _Float16* Bb = Bm + (size_t)n0 * K;

  auto stage = [&](int ks, int bi) {
#pragma unroll
    for (int it = 0; it < 2; ++it) {
      int c = tid + it * 256;
      int lrow = c >> 3;
      int sch = (c & 7) ^ (lrow & 7);
      int mrow = lrow * 2 + (sch >> 2), part = sch & 3;
      gload16(Ab + (size_t)mrow * K + ks * 32 + part * 8, &Ah[bi][c * 8]);
    }
    int c = tid;                       // 256 chunks for B (64 rows)
    int lrow = c >> 3;
    int sch = (c & 7) ^ (lrow & 7);
    int mrow = lrow * 2 + (sch >> 2), part = sch & 3;
    gload16(Bb + (size_t)mrow * K + ks * 32 + part * 8, &Bh[bi][c * 8]);
  };

  // read offsets: row R -> lds row R>>1, chunk ((R&1)*4+lg)^((R>>1)&7)
  const int rch = (((lr & 1) * 4 + lg) ^ (lr >> 1)) * 8;
  const int lrb = lr >> 1;

  stage(0, 0);
  const int ksteps = K >> 5;
  for (int ks = 0; ks < ksteps; ++ks) {
    __syncthreads();
    int cur = ks & 1;
    if (ks + 1 < ksteps) stage(ks + 1, cur ^ 1);

    h8 af[4], bf[2];
#pragma unroll
    for (int i = 0; i < 4; ++i)
      af[i] = *(const h8*)&Ah[cur][(wr / 2 + i * 8 + lrb) * 64 + rch];
#pragma unroll
    for (int j = 0; j < 2; ++j)
      bf[j] = *(const h8*)&Bh[cur][(wb * 8 + j * 16 + lrb) * 64 + rch];
#pragma unroll
    for (int i = 0; i < 4; ++i)
#pragma unroll
      for (int j = 0; j < 2; ++j) acc[i][j] = mfma16(af[i], bf[j], acc[i][j]);
  }

  // ---- fused RoPE epilogue: acc[i][0]=d=m, acc[i][1]=d=m+32, m=wb*16+lr ----
  const int s = bx >> 4;                  // 0=q 1=k 2=v
  const int hcol = bx & 15;
  _Float16* dst = (s == 0) ? qh : (s == 1) ? kh : vh;
  const float scl = (s == 0) ? QSCALE : 1.0f;
  const int m = wb * 16 + lr;             // 0..31
#pragma unroll
  for (int i = 0; i < 4; ++i)
#pragma unroll
    for (int r = 0; r < 4; ++r) {
      int row = m0 + wr + i * 16 + lg * 4 + r;
      int n = row & (SEQ - 1);
      _Float16* drow = dst + ((size_t)(((row >> 11) * NHEAD + hcol) * SEQ + n)) * HD;
      h2v o;
      if (s == 2) {
        o = {(_Float16)acc[i][0][r], (_Float16)acc[i][1][r]};
      } else {
        float c0 = cosT[n * 32 + m], sn0 = sinT[n * 32 + m];
        float a1 = acc[i][0][r], a2 = acc[i][1][r];
        o = {(_Float16)((a1 * c0 - a2 * sn0) * scl),     // d = m
             (_Float16)((a2 * c0 + a1 * sn0) * scl)};    // d = m+32
      }
      *(h2v*)&drow[m * 2] = o;          // permuted: pos 2m,2m+1
    }
}

// ---------------------------------------------------------------------------
// Out-proj GEMM: C[4096,1024] = A[4096,K] * Bm[1024,K]^T, fp32 out.
// 128x64 tile -> 512 blocks. Conflict-free LDS layout as gemm_qkv.
// ---------------------------------------------------------------------------
__global__ __launch_bounds__(256) void gemm_out(const _Float16* __restrict__ A,
                                                const _Float16* __restrict__ Bm,
                                                float* __restrict__ Cv) {
  const int K = DIM_C, N = DIM_C;
  __shared__ _Float16 Ah[2][64 * 64];
  __shared__ _Float16 Bh[2][32 * 64];
  const int tid = threadIdx.x;
  const int wave = tid >> 6, lane = tid & 63;
  const int lr = lane & 15, lg = lane >> 4;
  const int p = blockIdx.x;             // 0..511
  const int wg = (p & 7) * 64 + (p >> 3);
  const int bx = wg >> 5, by = wg & 31;
  const int m0 = by * 128, n0 = bx * 64;
  const int wr = (wave >> 1) * 64, wc = (wave & 1) * 32;

  const f4 zf = {0.f, 0.f, 0.f, 0.f};
  f4 acc[4][2];
#pragma unroll
  for (int i = 0; i < 4; ++i)
#pragma unroll
    for (int j = 0; j < 2; ++j) acc[i][j] = zf;

  const _Float16* Ab = A + (size_t)m0 * K;
  const _Float16* Bb = Bm + (size_t)n0 * K;

  auto stage = [&](int ks, int bi) {
#pragma unroll
    for (int it = 0; it < 2; ++it) {
      int c = tid + it * 256;
      int lrow = c >> 3;
      int sch = (c & 7) ^ (lrow & 7);
      int mrow = lrow * 2 + (sch >> 2), part = sch & 3;
      gload16(Ab + (size_t)mrow * K + ks * 32 + part * 8, &Ah[bi][c * 8]);
    }
    int c = tid;                       // 256 chunks for B (64 rows)
    int lrow = c >> 3;
    int sch = (c & 7) ^ (lrow & 7);
    int mrow = lrow * 2 + (sch >> 2), part = sch & 3;
    gload16(Bb + (size_t)mrow * K + ks * 32 + part * 8, &Bh[bi][c * 8]);
  };

  const int rch = (((lr & 1) * 4 + lg) ^ (lr >> 1)) * 8;
  const int lrb = lr >> 1;

  stage(0, 0);
  const int ksteps = K >> 5;
  for (int ks = 0; ks < ksteps; ++ks) {
    __syncthreads();
    int cur = ks & 1;
    if (ks + 1 < ksteps) stage(ks + 1, cur ^ 1);

    h8 af[4], bf[2];
#pragma unroll
    for (int i = 0; i < 4; ++i)
      af[i] = *(const h8*)&Ah[cur][(wr / 2 + i * 8 + lrb) * 64 + rch];
#pragma unroll
    for (int j = 0; j < 2; ++j)
      bf[j] = *(const h8*)&Bh[cur][(wc / 2 + j * 8 + lrb) * 64 + rch];
#pragma unroll
    for (int i = 0; i < 4; ++i)
#pragma unroll
      for (int j = 0; j < 2; ++j) acc[i][j] = mfma16(af[i], bf[j], acc[i][j]);
  }

#pragma unroll
  for (int i = 0; i < 4; ++i)
#pragma unroll
    for (int j = 0; j < 2; ++j)
#pragma unroll
      for (int r = 0; r < 4; ++r) {
        size_t row = (size_t)(m0 + wr + i * 16 + lg * 4 + r);
        int col = n0 + wc + j * 16 + lr;
        Cv[row * N + col] = acc[i][j][r];
      }
}

// ---------------------------------------------------------------------------
// V transpose + un-permute: permuted [bh][2048][64] -> canonical [bh][64][2048].
// Interleaved permutation: canonical d lives at position ((d&31)<<1)|(d>>5).
// ---------------------------------------------------------------------------
__global__ void vtrans_kernel(const _Float16* __restrict__ v, _Float16* __restrict__ vt) {
  int blk = blockIdx.x;            // 32 bh * 64 tiles
  int bh = blk >> 6, nt = blk & 63;
  int d = threadIdx.x & 63, w = threadIdx.x >> 6;
  int pp = ((d & 31) << 1) | (d >> 5);   // permuted position of canonical d
  int n0 = nt * 32 + w * 8;
  const _Float16* src = v + (size_t)bh * SEQ * HD;
  _Float16* dst = vt + ((size_t)bh * HD + d) * SEQ;
  h8 o;
#pragma unroll
  for (int j = 0; j < 8; ++j) o[j] = src[(size_t)(n0 + j) * HD + pp];
  *(h8*)(dst + n0) = o;
}

// ---------------------------------------------------------------------------
// Flash attention v14b: v12's EXACT instruction ordering (kf -> QK -> vf ->
// SM+PV; vf read AFTER the QK burst, which is what kept v12 at 124 VGPR)
// combined with the round-18-verified single-buffer-V barrier scheme:
//   barrier A (K(t),V(t) visible) -> stageK(t+1) -> read kf -> QK ->
//   read vf -> barrier B (vf reads done) -> stageV(t+1) -> SM+PV
// LDS 64 KB -> 48 KB -> 3 blocks/CU (if VGPR <= 170). Default launch bounds
// (min-waves bounds proven toxic in rounds 18/19). All index math identical
// to verified v12 / v13b.
// ---------------------------------------------------------------------------
__global__ __launch_bounds__(256) void attn_kernel(const _Float16* __restrict__ qh,
                                                   const _Float16* __restrict__ kh,
                                                   const _Float16* __restrict__ vt,
                                                   _Float16* __restrict__ aoh) {
  // one LDS arena, aliased: K (2 bufs) + V (1 buf) during the loop, partials after
  __shared__ __align__(16) char smem[49152];
  _Float16* KtB = (_Float16*)smem;               // [2][128*64]  (32 KB)
  _Float16* Vt  = (_Float16*)(smem + 32768);     // [64*128]     (16 KB)

  const int tid = threadIdx.x, wave = tid >> 6, lane = tid & 63;
  const int lr = lane & 15, lg = lane >> 4;
  const int qw = wave >> 1, kvw = wave & 1;
  const int p = blockIdx.x;                  // 0..511
  const int wg = (p & 7) * 64 + (p >> 3);    // XCD grouping (bijective for 512)
  const int bh = wg >> 4;                    // 0..31
  const int qt = wg & 15;
  const int b = bh >> 4, h = bh & 15;

  const _Float16* Qb = qh + (size_t)bh * SEQ * HD;
  const _Float16* Kb = kh + (size_t)bh * SEQ * HD;
  const _Float16* Vb = vt + (size_t)bh * HD * SEQ;     // [64][2048]
  const int q0 = qt * 128 + qw * 64;

  // swizzled read chunk offsets for this wave's kv half
  int kOf[2], vOf[2];
#pragma unroll
  for (int cc = 0; cc < 2; ++cc) {
    kOf[cc] = ((cc * 4 + lg) ^ (lr & 7)) * 8;
    vOf[cc] = ((kvw * 8 + cc * 4 + lg) ^ lr) * 8;
  }

  // Q frags (Y operand): 64 q rows = 4 r2 blocks
  h8 aq[4][2];
#pragma unroll
  for (int r2 = 0; r2 < 4; ++r2)
#pragma unroll
    for (int c = 0; c < 2; ++c)
      aq[r2][c] = *(const h8*)(Qb + (size_t)(q0 + r2 * 16 + lr) * HD + c * 32 + lg * 8);

  const h8 onesv = {(_Float16)1.f, (_Float16)1.f, (_Float16)1.f, (_Float16)1.f,
                    (_Float16)1.f, (_Float16)1.f, (_Float16)1.f, (_Float16)1.f};
  const f4 zf = {0.f, 0.f, 0.f, 0.f};
  f4 lacc[4] = {zf, zf, zf, zf};
  f4 acc[4][4];                        // [r2][dt]: col q=lr, rows d=dt*16+lg*4+r
#pragma unroll
  for (int r2 = 0; r2 < 4; ++r2)
#pragma unroll
    for (int dt = 0; dt < 4; ++dt) acc[r2][dt] = zf;

  auto stageK = [&](int kt, int bi) {
    const _Float16* Ks = Kb + (size_t)kt * 128 * HD;
    _Float16* kb = KtB + bi * 8192;
#pragma unroll
    for (int it = 0; it < 4; ++it) {
      int c = tid + it * 256;
      int krow = c >> 3, kpart = c & 7;
      int ksp = kpart ^ (krow & 7);
      gload16(Ks + (size_t)krow * HD + ksp * 8, kb + c * 8);
    }
  };
  auto stageV = [&](int kt) {
    const _Float16* Vs = Vb + kt * 128;
#pragma unroll
    for (int it = 0; it < 4; ++it) {
      int c = tid + it * 256;
      int vrow = c >> 4, vpart = c & 15;
      int vsp = vpart ^ (vrow & 15);
      gload16(Vs + (size_t)vrow * SEQ + vsp * 8, Vt + c * 8);
    }
  };

  stageK(0, 0);
  stageV(0);
  for (int t = 0; t < SEQ / 128; ++t) {
    __syncthreads();                   // barrier A: K(t) + V(t) staged & visible
    const int cur = t & 1;
    if (t + 1 < SEQ / 128) stageK(t + 1, cur ^ 1);

    // ---- K frags for this wave's kv half (8 b128) ----
    h8 kf[4][2];
    const _Float16* Krow = KtB + cur * 8192 + (kvw * 64 + lr) * 64;
#pragma unroll
    for (int ct = 0; ct < 4; ++ct)
#pragma unroll
      for (int cc = 0; cc < 2; ++cc)
        kf[ct][cc] = *(const h8*)(Krow + ct * 16 * 64 + kOf[cc]);

    // ---- QK burst: 32 consecutive MFMAs, St[4 r2][4 ct] ----
    f4 St[4][4];
    __builtin_amdgcn_s_setprio(1);
#pragma unroll
    for (int r2 = 0; r2 < 4; ++r2)
#pragma unroll
      for (int ct = 0; ct < 4; ++ct) {
        f4 z = mfma16(kf[ct][0], aq[r2][0], zf);
        St[r2][ct] = mfma16(kf[ct][1], aq[r2][1], z);
      }
    __builtin_amdgcn_s_setprio(0);

    // ---- V frags for this wave's kv half (8 b128), AFTER QK (v12 order) ----
    h8 vf[4][2];
    const _Float16* Vrow = Vt + lr * 128;
#pragma unroll
    for (int dt = 0; dt < 4; ++dt)
#pragma unroll
      for (int cc = 0; cc < 2; ++cc)
        vf[dt][cc] = *(const h8*)(Vrow + dt * 16 * 128 + vOf[cc]);

    // ---- barrier B: all waves' vf(t) reads complete -> V buffer free ----
    __syncthreads();
    if (t + 1 < SEQ / 128) stageV(t + 1);   // flies under SM+PV below

    // ---- SM + PV per r2 ----
#pragma unroll
    for (int r2 = 0; r2 < 4; ++r2) {
      unsigned w[4][2];
#pragma unroll
      for (int ct = 0; ct < 4; ++ct) {
        w[ct][0] = pk2(EXP2(St[r2][ct][0]), EXP2(St[r2][ct][1]));
        w[ct][1] = pk2(EXP2(St[r2][ct][2]), EXP2(St[r2][ct][3]));
      }
      // butterfly: C-layout (k=ct*16+lg*4+r) -> B-frag (k=c*32+lg*8+j)
      swap32(w[0][0], w[1][0]); swap32(w[0][1], w[1][1]);
      swap32(w[2][0], w[3][0]); swap32(w[2][1], w[3][1]);
      swap16(w[0][0], w[1][0]); swap16(w[0][1], w[1][1]);
      swap16(w[2][0], w[3][0]); swap16(w[2][1], w[3][1]);
      u4v pw0 = {w[0][0], w[0][1], w[1][0], w[1][1]};
      u4v pw1 = {w[2][0], w[2][1], w[3][0], w[3][1]};
      h8 pa0, pa1;
      __builtin_memcpy(&pa0, &pw0, 16);
      __builtin_memcpy(&pa1, &pw1, 16);

      __builtin_amdgcn_s_setprio(1);
      lacc[r2] = mfma16(onesv, pa0, lacc[r2]);
      lacc[r2] = mfma16(onesv, pa1, lacc[r2]);
#pragma unroll
      for (int dt = 0; dt < 4; ++dt) {
        acc[r2][dt] = mfma16(vf[dt][0], pa0, acc[r2][dt]);
        acc[r2][dt] = mfma16(vf[dt][1], pa1, acc[r2][dt]);
      }
      __builtin_amdgcn_s_setprio(0);
    }
  }

  // ---- cross-wave combine: kv-partials are exactly additive ----
  __syncthreads();                     // all loop LDS traffic complete
  float* pl = (float*)smem;            // [2 qw][64 q][65] f32 = 33280 B
  float* lp = (float*)(smem + 34816);  // [2 qw][64 q] f32 (within 48 KB arena)

  if (kvw == 1) {
#pragma unroll
    for (int r2 = 0; r2 < 4; ++r2) {
      int ql = qw * 64 + r2 * 16 + lr;
#pragma unroll
      for (int dt = 0; dt < 4; ++dt)
        *(f4*)&pl[(size_t)ql * 65 + dt * 16 + lg * 4] = acc[r2][dt];
      if (lg == 0) lp[ql] = lacc[r2][0];
    }
  }
  __syncthreads();
  if (kvw == 0) {
#pragma unroll
    for (int r2 = 0; r2 < 4; ++r2) {
      int ql = qw * 64 + r2 * 16 + lr;
      float lt = lacc[r2][0] + lp[ql];
      float inv = 1.0f / lt;
      int q = q0 + r2 * 16 + lr;
#pragma unroll
      for (int dt = 0; dt < 4; ++dt) {
        f4 oth = *(const f4*)&pl[(size_t)ql * 65 + dt * 16 + lg * 4];
        f4 s = acc[r2][dt] + oth;
        h4v o = {(_Float16)(s[0] * inv), (_Float16)(s[1] * inv),
                 (_Float16)(s[2] * inv), (_Float16)(s[3] * inv)};
        *(h4v*)&aoh[((size_t)(b * SEQ + q)) * DIM_C + h * HD + dt * 16 + lg * 4] = o;
      }
    }
  }
}

// ---------------------------------------------------------------------------
// launch
// ---------------------------------------------------------------------------
extern "C" void kernel_launch(void* const* d_in, const int* in_sizes, int n_in,
                              void* d_out, int out_size, void* d_ws, size_t ws_size,
                              hipStream_t stream) {
  const float* x     = (const float*)d_in[0];
  const float* w_qkv = (const float*)d_in[1];
  const float* w_out = (const float*)d_in[2];
  float* out = (float*)d_out;

  char* w = (char*)d_ws;
  _Float16* xh    = (_Float16*)(w + 0);           //  8 MB  [4096][1024]
  _Float16* wqkvh = (_Float16*)(w + 8388608);     //  6 MB  [3072][1024]
  _Float16* wouth = (_Float16*)(w + 14680064);    //  2 MB  [1024][1024]
  _Float16* qhp   = (_Float16*)(w + 16777216);    //  8 MB  [2][16][2048][64]
  _Float16* khp   = (_Float16*)(w + 25165824);    //  8 MB
  _Float16* vhp   = (_Float16*)(w + 33554432);    //  8 MB
  _Float16* vtp   = (_Float16*)(w + 41943040);    //  8 MB  [2][16][64][2048]
  _Float16* aohp  = (_Float16*)(w + 50331648);    //  8 MB  [4096][1024]
  float*    cosT  = (float*)(w + 58720256);       // 256 KB [2048][32]
  float*    sinT  = (float*)(w + 58982400);       // 256 KB

  prep_kernel<<<(CVT_TOT + SEQ * 32) / 256, 256, 0, stream>>>(
      x, w_qkv, w_out, xh, wqkvh, wouth, cosT, sinT);

  gemm_qkv<<<1536, 256, 0, stream>>>(xh, wqkvh, cosT, sinT, qhp, khp, vhp);

  vtrans_kernel<<<32 * 64, 256, 0, stream>>>(vhp, vtp);

  attn_kernel<<<32 * 16, 256, 0, stream>>>(qhp, khp, vtp, aohp);

  gemm_out<<<512, 256, 0, stream>>>(aohp, wouth, out);
}

// Round 22
// 127.701 us; speedup vs baseline: 1.1701x; 1.1701x over previous
//
#include <hip/hip_runtime.h>
#include <stdint.h>

// ---------------------------------------------------------------------------
// MultiHeadAttention fused pipeline, fp16 MFMA, fp32 accumulation.
// B=2, N=2048, DIM=1024, H=16, hd=64.
// Q/K are stored in an INTERLEAVED PERMUTED d-layout: position 2m holds d=m,
// position 2m+1 holds d=m+32 (m=0..31). QK^T is invariant since both operands
// use the same permutation. V is stored permuted too and un-permuted inside
// vtrans (its reads are scalar gathers anyway).
// ---------------------------------------------------------------------------

#define BATCH 2
#define SEQ   2048
#define DIM_C 1024
#define NHEAD 16
#define HD    64
#define MTOT  (BATCH * SEQ)      // 4096
#define NQKV  (3 * DIM_C)        // 3072
// 0.125 * log2(e): QK^T lands in log2 domain -> exp2 (single v_exp_f32)
#define QSCALE 0.1803368801111204f

typedef _Float16 h8 __attribute__((ext_vector_type(8)));
typedef _Float16 h4v __attribute__((ext_vector_type(4)));
typedef _Float16 h2v __attribute__((ext_vector_type(2)));
typedef float    f4 __attribute__((ext_vector_type(4)));
typedef unsigned int u4v __attribute__((ext_vector_type(4)));

#if __has_builtin(__builtin_amdgcn_exp2f)
#define EXP2(x) __builtin_amdgcn_exp2f(x)
#else
#define EXP2(x) exp2f(x)
#endif

__device__ __forceinline__ f4 mfma16(h8 a, h8 b, f4 c) {
  return __builtin_amdgcn_mfma_f32_16x16x32_f16(a, b, c, 0, 0, 0);
}

// pack two f32 -> u32 of two f16
__device__ __forceinline__ unsigned pk2(float a, float b) {
  auto t = __builtin_amdgcn_cvt_pkrtz(a, b);
  unsigned u;
  __builtin_memcpy(&u, &t, 4);
  return u;
}

// a' = {a.lo32, b.lo32}; b' = {a.hi32, b.hi32}
__device__ __forceinline__ void swap32(unsigned& a, unsigned& b) {
#if __has_builtin(__builtin_amdgcn_permlane32_swap)
  typedef unsigned u2_ __attribute__((ext_vector_type(2)));
  u2_ r = __builtin_amdgcn_permlane32_swap(a, b, false, false);
  a = r[0]; b = r[1];
#else
  const bool hi = (threadIdx.x & 32) != 0;
  unsigned sa = __shfl_xor(a, 32), sb = __shfl_xor(b, 32);
  unsigned na = hi ? sb : a, nb = hi ? b : sa;
  a = na; b = nb;
#endif
}
__device__ __forceinline__ void swap16(unsigned& a, unsigned& b) {
#if __has_builtin(__builtin_amdgcn_permlane16_swap)
  typedef unsigned u2_ __attribute__((ext_vector_type(2)));
  u2_ r = __builtin_amdgcn_permlane16_swap(a, b, false, false);
  a = r[0]; b = r[1];
#else
  const bool hi = (threadIdx.x & 16) != 0;
  unsigned sa = __shfl_xor(a, 16), sb = __shfl_xor(b, 16);
  unsigned na = hi ? sb : a, nb = hi ? b : sa;
  a = na; b = nb;
#endif
}

// async global->LDS, 16B per lane; LDS dest must be linear in lane order.
__device__ __forceinline__ void gload16(const _Float16* g, _Float16* l) {
  __builtin_amdgcn_global_load_lds(
      (const __attribute__((address_space(1))) void*)g,
      (__attribute__((address_space(3))) void*)l, 16, 0, 0);
}

// ---------------------------------------------------------------------------
// Fused prep: fp32->fp16 for x / w_qkv / w_out (float4 chunks) + RoPE tables.
// ---------------------------------------------------------------------------
#define N4X  1048576                 // 4096*1024/4
#define N4WQ 786432                  // 3072*1024/4
#define N4WO 262144                  // 1024*1024/4
#define CVT_TOT (N4X + N4WQ + N4WO)  // 2097152
__global__ void prep_kernel(const float* __restrict__ x,
                            const float* __restrict__ wq,
                            const float* __restrict__ wo,
                            _Float16* __restrict__ xh,
                            _Float16* __restrict__ wqh,
                            _Float16* __restrict__ woh,
                            float* __restrict__ cosT, float* __restrict__ sinT) {
  int idx = blockIdx.x * blockDim.x + threadIdx.x;   // CVT_TOT + 65536 exact
  if (idx < CVT_TOT) {
    const float* s; _Float16* d; int i;
    if (idx < N4X) { s = x; d = xh; i = idx; }
    else if (idx < N4X + N4WQ) { s = wq; d = wqh; i = idx - N4X; }
    else { s = wo; d = woh; i = idx - (N4X + N4WQ); }
    float4 v = reinterpret_cast<const float4*>(s)[i];
    h4v o = {(_Float16)v.x, (_Float16)v.y, (_Float16)v.z, (_Float16)v.w};
    reinterpret_cast<h4v*>(d)[i] = o;
  } else {
    int t = idx - CVT_TOT;           // 0..65535: SEQ x 32
    int n = t >> 5, j = t & 31;
    float inv = powf(10000.0f, -(float)(2 * j) / 64.0f);
    float a = (float)n * inv;
    cosT[t] = cosf(a);
    sinT[t] = sinf(a);
  }
}

// ---------------------------------------------------------------------------
// QKV GEMM with fused RoPE epilogue. 128x64 tile (one head per block) ->
// 1536 blocks. Wave columns: wb = wave&1 selects {wb*16..+15} U {wb*16+32..+47}
// so the RoPE pair (d, d+32) = (acc[i][0], acc[i][1]) is thread-local.
// Conflict-free LDS + XOR chunk swizzle (both sides). Epilogue: one h2 (4B)
// store per row in the interleaved permuted d-layout.
// ---------------------------------------------------------------------------
__global__ __launch_bounds__(256) void gemm_qkv(const _Float16* __restrict__ A,
                                                const _Float16* __restrict__ Bm,
                                                const float* __restrict__ cosT,
                                                const float* __restrict__ sinT,
                                                _Float16* __restrict__ qh,
                                                _Float16* __restrict__ kh,
                                                _Float16* __restrict__ vh) {
  const int K = DIM_C;
  __shared__ _Float16 Ah[2][64 * 64];
  __shared__ _Float16 Bh[2][32 * 64];
  const int tid = threadIdx.x;
  const int wave = tid >> 6, lane = tid & 63;
  const int lr = lane & 15, lg = lane >> 4;
  const int p = blockIdx.x;             // 0..1535
  const int wg = (p & 7) * 192 + (p >> 3);
  const int bx = wg >> 5, by = wg & 31; // bx 0..47, by 0..31
  const int m0 = by * 128, n0 = bx * 64;
  const int wr = (wave >> 1) * 64, wb = wave & 1;

  const f4 zf = {0.f, 0.f, 0.f, 0.f};
  f4 acc[4][2];
#pragma unroll
  for (int i = 0; i < 4; ++i)
#pragma unroll
    for (int j = 0; j < 2; ++j) acc[i][j] = zf;

  const _Float16* Ab = A + (size_t)m0 * K;
  const _Float16* Bb = Bm + (size_t)n0 * K;

  auto stage = [&](int ks, int bi) {
#pragma unroll
    for (int it = 0; it < 2; ++it) {
      int c = tid + it * 256;
      int lrow = c >> 3;
      int sch = (c & 7) ^ (lrow & 7);
      int mrow = lrow * 2 + (sch >> 2), part = sch & 3;
      gload16(Ab + (size_t)mrow * K + ks * 32 + part * 8, &Ah[bi][c * 8]);
    }
    int c = tid;                       // 256 chunks for B (64 rows)
    int lrow = c >> 3;
    int sch = (c & 7) ^ (lrow & 7);
    int mrow = lrow * 2 + (sch >> 2), part = sch & 3;
    gload16(Bb + (size_t)mrow * K + ks * 32 + part * 8, &Bh[bi][c * 8]);
  };

  // read offsets: row R -> lds row R>>1, chunk ((R&1)*4+lg)^((R>>1)&7)
  const int rch = (((lr & 1) * 4 + lg) ^ (lr >> 1)) * 8;
  const int lrb = lr >> 1;

  stage(0, 0);
  const int ksteps = K >> 5;
  for (int ks = 0; ks < ksteps; ++ks) {
    __syncthreads();
    int cur = ks & 1;
    if (ks + 1 < ksteps) stage(ks + 1, cur ^ 1);

    h8 af[4], bf[2];
#pragma unroll
    for (int i = 0; i < 4; ++i)
      af[i] = *(const h8*)&Ah[cur][(wr / 2 + i * 8 + lrb) * 64 + rch];
#pragma unroll
    for (int j = 0; j < 2; ++j)
      bf[j] = *(const h8*)&Bh[cur][(wb * 8 + j * 16 + lrb) * 64 + rch];
#pragma unroll
    for (int i = 0; i < 4; ++i)
#pragma unroll
      for (int j = 0; j < 2; ++j) acc[i][j] = mfma16(af[i], bf[j], acc[i][j]);
  }

  // ---- fused RoPE epilogue: acc[i][0]=d=m, acc[i][1]=d=m+32, m=wb*16+lr ----
  const int s = bx >> 4;                  // 0=q 1=k 2=v
  const int hcol = bx & 15;
  _Float16* dst = (s == 0) ? qh : (s == 1) ? kh : vh;
  const float scl = (s == 0) ? QSCALE : 1.0f;
  const int m = wb * 16 + lr;             // 0..31
#pragma unroll
  for (int i = 0; i < 4; ++i)
#pragma unroll
    for (int r = 0; r < 4; ++r) {
      int row = m0 + wr + i * 16 + lg * 4 + r;
      int n = row & (SEQ - 1);
      _Float16* drow = dst + ((size_t)(((row >> 11) * NHEAD + hcol) * SEQ + n)) * HD;
      h2v o;
      if (s == 2) {
        o = {(_Float16)acc[i][0][r], (_Float16)acc[i][1][r]};
      } else {
        float c0 = cosT[n * 32 + m], sn0 = sinT[n * 32 + m];
        float a1 = acc[i][0][r], a2 = acc[i][1][r];
        o = {(_Float16)((a1 * c0 - a2 * sn0) * scl),     // d = m
             (_Float16)((a2 * c0 + a1 * sn0) * scl)};    // d = m+32
      }
      *(h2v*)&drow[m * 2] = o;          // permuted: pos 2m,2m+1
    }
}

// ---------------------------------------------------------------------------
// Out-proj GEMM: C[4096,1024] = A[4096,K] * Bm[1024,K]^T, fp32 out.
// 128x64 tile -> 512 blocks. Conflict-free LDS layout as gemm_qkv.
// ---------------------------------------------------------------------------
__global__ __launch_bounds__(256) void gemm_out(const _Float16* __restrict__ A,
                                                const _Float16* __restrict__ Bm,
                                                float* __restrict__ Cv) {
  const int K = DIM_C, N = DIM_C;
  __shared__ _Float16 Ah[2][64 * 64];
  __shared__ _Float16 Bh[2][32 * 64];
  const int tid = threadIdx.x;
  const int wave = tid >> 6, lane = tid & 63;
  const int lr = lane & 15, lg = lane >> 4;
  const int p = blockIdx.x;             // 0..511
  const int wg = (p & 7) * 64 + (p >> 3);
  const int bx = wg >> 5, by = wg & 31;
  const int m0 = by * 128, n0 = bx * 64;
  const int wr = (wave >> 1) * 64, wc = (wave & 1) * 32;

  const f4 zf = {0.f, 0.f, 0.f, 0.f};
  f4 acc[4][2];
#pragma unroll
  for (int i = 0; i < 4; ++i)
#pragma unroll
    for (int j = 0; j < 2; ++j) acc[i][j] = zf;

  const _Float16* Ab = A + (size_t)m0 * K;
  const _Float16* Bb = Bm + (size_t)n0 * K;

  auto stage = [&](int ks, int bi) {
#pragma unroll
    for (int it = 0; it < 2; ++it) {
      int c = tid + it * 256;
      int lrow = c >> 3;
      int sch = (c & 7) ^ (lrow & 7);
      int mrow = lrow * 2 + (sch >> 2), part = sch & 3;
      gload16(Ab + (size_t)mrow * K + ks * 32 + part * 8, &Ah[bi][c * 8]);
    }
    int c = tid;                       // 256 chunks for B (64 rows)
    int lrow = c >> 3;
    int sch = (c & 7) ^ (lrow & 7);
    int mrow = lrow * 2 + (sch >> 2), part = sch & 3;
    gload16(Bb + (size_t)mrow * K + ks * 32 + part * 8, &Bh[bi][c * 8]);
  };

  const int rch = (((lr & 1) * 4 + lg) ^ (lr >> 1)) * 8;
  const int lrb = lr >> 1;

  stage(0, 0);
  const int ksteps = K >> 5;
  for (int ks = 0; ks < ksteps; ++ks) {
    __syncthreads();
    int cur = ks & 1;
    if (ks + 1 < ksteps) stage(ks + 1, cur ^ 1);

    h8 af[4], bf[2];
#pragma unroll
    for (int i = 0; i < 4; ++i)
      af[i] = *(const h8*)&Ah[cur][(wr / 2 + i * 8 + lrb) * 64 + rch];
#pragma unroll
    for (int j = 0; j < 2; ++j)
      bf[j] = *(const h8*)&Bh[cur][(wc / 2 + j * 8 + lrb) * 64 + rch];
#pragma unroll
    for (int i = 0; i < 4; ++i)
#pragma unroll
      for (int j = 0; j < 2; ++j) acc[i][j] = mfma16(af[i], bf[j], acc[i][j]);
  }

#pragma unroll
  for (int i = 0; i < 4; ++i)
#pragma unroll
    for (int j = 0; j < 2; ++j)
#pragma unroll
      for (int r = 0; r < 4; ++r) {
        size_t row = (size_t)(m0 + wr + i * 16 + lg * 4 + r);
        int col = n0 + wc + j * 16 + lr;
        Cv[row * N + col] = acc[i][j][r];
      }
}

// ---------------------------------------------------------------------------
// V transpose + un-permute: permuted [bh][2048][64] -> canonical [bh][64][2048].
// Interleaved permutation: canonical d lives at position ((d&31)<<1)|(d>>5).
// ---------------------------------------------------------------------------
__global__ void vtrans_kernel(const _Float16* __restrict__ v, _Float16* __restrict__ vt) {
  int blk = blockIdx.x;            // 32 bh * 64 tiles
  int bh = blk >> 6, nt = blk & 63;
  int d = threadIdx.x & 63, w = threadIdx.x >> 6;
  int pp = ((d & 31) << 1) | (d >> 5);   // permuted position of canonical d
  int n0 = nt * 32 + w * 8;
  const _Float16* src = v + (size_t)bh * SEQ * HD;
  _Float16* dst = vt + ((size_t)bh * HD + d) * SEQ;
  h8 o;
#pragma unroll
  for (int j = 0; j < 8; ++j) o[j] = src[(size_t)(n0 + j) * HD + pp];
  *(h8*)(dst + n0) = o;
}

// ---------------------------------------------------------------------------
// Flash attention v12 (verified passing, 512 blocks): 2x2 wave decomposition
// of a 128q x 128kv tile (qw: 64-q half, kvw: 64-kv half), KVB=128, full-KV
// per block, XCD-grouped swizzle, double-buffered global_load_lds with XOR
// chunk swizzle, swapped QK^T (q lane-local), fixed-shift exact softmax
// (P = 2^S), in-register P via cvt_pkrtz + permlane swaps, ones-row MFMA
// l-sum, cross-wave additive combine through LDS. Q/K in permuted d-layout
// (opaque to this kernel -- QK^T invariant); V^T canonical.
// ---------------------------------------------------------------------------
__global__ __launch_bounds__(256, 2) void attn_kernel(const _Float16* __restrict__ qh,
                                                      const _Float16* __restrict__ kh,
                                                      const _Float16* __restrict__ vt,
                                                      _Float16* __restrict__ aoh) {
  // one LDS arena, aliased: K/V tiles during the loop, partials after it
  __shared__ __align__(16) char smem[65536];
  _Float16* KtB = (_Float16*)smem;               // [2][128*64]  (32 KB)
  _Float16* VtB = (_Float16*)(smem + 32768);     // [2][64*128]  (32 KB)

  const int tid = threadIdx.x, wave = tid >> 6, lane = tid & 63;
  const int lr = lane & 15, lg = lane >> 4;
  const int qw = wave >> 1, kvw = wave & 1;
  const int p = blockIdx.x;                  // 0..511
  const int wg = (p & 7) * 64 + (p >> 3);    // XCD grouping (bijective for 512)
  const int bh = wg >> 4;                    // 0..31
  const int qt = wg & 15;
  const int b = bh >> 4, h = bh & 15;

  const _Float16* Qb = qh + (size_t)bh * SEQ * HD;
  const _Float16* Kb = kh + (size_t)bh * SEQ * HD;
  const _Float16* Vb = vt + (size_t)bh * HD * SEQ;     // [64][2048]
  const int q0 = qt * 128 + qw * 64;

  // swizzled read chunk offsets for this wave's kv half
  int kOf[2], vOf[2];
#pragma unroll
  for (int cc = 0; cc < 2; ++cc) {
    kOf[cc] = ((cc * 4 + lg) ^ (lr & 7)) * 8;
    vOf[cc] = ((kvw * 8 + cc * 4 + lg) ^ lr) * 8;
  }

  // Q frags (Y operand): 64 q rows = 4 r2 blocks
  h8 aq[4][2];
#pragma unroll
  for (int r2 = 0; r2 < 4; ++r2)
#pragma unroll
    for (int c = 0; c < 2; ++c)
      aq[r2][c] = *(const h8*)(Qb + (size_t)(q0 + r2 * 16 + lr) * HD + c * 32 + lg * 8);

  const h8 onesv = {(_Float16)1.f, (_Float16)1.f, (_Float16)1.f, (_Float16)1.f,
                    (_Float16)1.f, (_Float16)1.f, (_Float16)1.f, (_Float16)1.f};
  const f4 zf = {0.f, 0.f, 0.f, 0.f};
  f4 lacc[4] = {zf, zf, zf, zf};
  f4 acc[4][4];                        // [r2][dt]: col q=lr, rows d=dt*16+lg*4+r
#pragma unroll
  for (int r2 = 0; r2 < 4; ++r2)
#pragma unroll
    for (int dt = 0; dt < 4; ++dt) acc[r2][dt] = zf;

  auto stage = [&](int kt, int bi) {
    const _Float16* Ks = Kb + (size_t)kt * 128 * HD;
    const _Float16* Vs = Vb + kt * 128;
    _Float16* kb = KtB + bi * 8192;
    _Float16* vb = VtB + bi * 8192;
#pragma unroll
    for (int it = 0; it < 4; ++it) {
      int c = tid + it * 256;
      int krow = c >> 3, kpart = c & 7;
      int ksp = kpart ^ (krow & 7);
      gload16(Ks + (size_t)krow * HD + ksp * 8, kb + c * 8);
      int vrow = c >> 4, vpart = c & 15;
      int vsp = vpart ^ (vrow & 15);
      gload16(Vs + (size_t)vrow * SEQ + vsp * 8, vb + c * 8);
    }
  };

  stage(0, 0);
  for (int t = 0; t < SEQ / 128; ++t) {
    __syncthreads();                   // drains vmcnt -> stage(t) visible
    const int cur = t & 1;
    if (t + 1 < SEQ / 128) stage(t + 1, cur ^ 1);

    // ---- K frags for this wave's kv half (8 b128) ----
    h8 kf[4][2];
    const _Float16* Krow = KtB + cur * 8192 + (kvw * 64 + lr) * 64;
#pragma unroll
    for (int ct = 0; ct < 4; ++ct)
#pragma unroll
      for (int cc = 0; cc < 2; ++cc)
        kf[ct][cc] = *(const h8*)(Krow + ct * 16 * 64 + kOf[cc]);

    // ---- QK burst: 32 consecutive MFMAs, St[4 r2][4 ct] ----
    f4 St[4][4];
    __builtin_amdgcn_s_setprio(1);
#pragma unroll
    for (int r2 = 0; r2 < 4; ++r2)
#pragma unroll
      for (int ct = 0; ct < 4; ++ct) {
        f4 z = mfma16(kf[ct][0], aq[r2][0], zf);
        St[r2][ct] = mfma16(kf[ct][1], aq[r2][1], z);
      }
    __builtin_amdgcn_s_setprio(0);

    // ---- V frags for this wave's kv half (8 b128) ----
    h8 vf[4][2];
    const _Float16* Vrow = VtB + cur * 8192 + lr * 128;
#pragma unroll
    for (int dt = 0; dt < 4; ++dt)
#pragma unroll
      for (int cc = 0; cc < 2; ++cc)
        vf[dt][cc] = *(const h8*)(Vrow + dt * 16 * 128 + vOf[cc]);

    // ---- SM + PV per r2 ----
#pragma unroll
    for (int r2 = 0; r2 < 4; ++r2) {
      unsigned w[4][2];
#pragma unroll
      for (int ct = 0; ct < 4; ++ct) {
        w[ct][0] = pk2(EXP2(St[r2][ct][0]), EXP2(St[r2][ct][1]));
        w[ct][1] = pk2(EXP2(St[r2][ct][2]), EXP2(St[r2][ct][3]));
      }
      // butterfly: C-layout (k=ct*16+lg*4+r) -> B-frag (k=c*32+lg*8+j)
      swap32(w[0][0], w[1][0]); swap32(w[0][1], w[1][1]);
      swap32(w[2][0], w[3][0]); swap32(w[2][1], w[3][1]);
      swap16(w[0][0], w[1][0]); swap16(w[0][1], w[1][1]);
      swap16(w[2][0], w[3][0]); swap16(w[2][1], w[3][1]);
      u4v pw0 = {w[0][0], w[0][1], w[1][0], w[1][1]};
      u4v pw1 = {w[2][0], w[2][1], w[3][0], w[3][1]};
      h8 pa0, pa1;
      __builtin_memcpy(&pa0, &pw0, 16);
      __builtin_memcpy(&pa1, &pw1, 16);

      __builtin_amdgcn_s_setprio(1);
      lacc[r2] = mfma16(onesv, pa0, lacc[r2]);
      lacc[r2] = mfma16(onesv, pa1, lacc[r2]);
#pragma unroll
      for (int dt = 0; dt < 4; ++dt) {
        acc[r2][dt] = mfma16(vf[dt][0], pa0, acc[r2][dt]);
        acc[r2][dt] = mfma16(vf[dt][1], pa1, acc[r2][dt]);
      }
      __builtin_amdgcn_s_setprio(0);
    }
  }

  // ---- cross-wave combine: kv-partials are exactly additive ----
  __syncthreads();                     // all reads of Kt/Vt complete
  float* pl = (float*)smem;            // [2 qw][64 q][65] f32 = 33280 B
  float* lp = (float*)(smem + 34816);  // [2 qw][64 q] f32 (dead Vt[0] space)

  if (kvw == 1) {
#pragma unroll
    for (int r2 = 0; r2 < 4; ++r2) {
      int ql = qw * 64 + r2 * 16 + lr;
#pragma unroll
      for (int dt = 0; dt < 4; ++dt)
        *(f4*)&pl[(size_t)ql * 65 + dt * 16 + lg * 4] = acc[r2][dt];
      if (lg == 0) lp[ql] = lacc[r2][0];
    }
  }
  __syncthreads();
  if (kvw == 0) {
#pragma unroll
    for (int r2 = 0; r2 < 4; ++r2) {
      int ql = qw * 64 + r2 * 16 + lr;
      float lt = lacc[r2][0] + lp[ql];
      float inv = 1.0f / lt;
      int q = q0 + r2 * 16 + lr;
#pragma unroll
      for (int dt = 0; dt < 4; ++dt) {
        f4 oth = *(const f4*)&pl[(size_t)ql * 65 + dt * 16 + lg * 4];
        f4 s = acc[r2][dt] + oth;
        h4v o = {(_Float16)(s[0] * inv), (_Float16)(s[1] * inv),
                 (_Float16)(s[2] * inv), (_Float16)(s[3] * inv)};
        *(h4v*)&aoh[((size_t)(b * SEQ + q)) * DIM_C + h * HD + dt * 16 + lg * 4] = o;
      }
    }
  }
}

// ---------------------------------------------------------------------------
// launch
// ---------------------------------------------------------------------------
extern "C" void kernel_launch(void* const* d_in, const int* in_sizes, int n_in,
                              void* d_out, int out_size, void* d_ws, size_t ws_size,
                              hipStream_t stream) {
  const float* x     = (const float*)d_in[0];
  const float* w_qkv = (const float*)d_in[1];
  const float* w_out = (const float*)d_in[2];
  float* out = (float*)d_out;

  char* w = (char*)d_ws;
  _Float16* xh    = (_Float16*)(w + 0);           //  8 MB  [4096][1024]
  _Float16* wqkvh = (_Float16*)(w + 8388608);     //  6 MB  [3072][1024]
  _Float16* wouth = (_Float16*)(w + 14680064);    //  2 MB  [1024][1024]
  _Float16* qhp   = (_Float16*)(w + 16777216);    //  8 MB  [2][16][2048][64]
  _Float16* khp   = (_Float16*)(w + 25165824);    //  8 MB
  _Float16* vhp   = (_Float16*)(w + 33554432);    //  8 MB
  _Float16* vtp   = (_Float16*)(w + 41943040);    //  8 MB  [2][16][64][2048]
  _Float16* aohp  = (_Float16*)(w + 50331648);    //  8 MB  [4096][1024]
  float*    cosT  = (float*)(w + 58720256);       // 256 KB [2048][32]
  float*    sinT  = (float*)(w + 58982400);       // 256 KB

  prep_kernel<<<(CVT_TOT + SEQ * 32) / 256, 256, 0, stream>>>(
      x, w_qkv, w_out, xh, wqkvh, wouth, cosT, sinT);

  gemm_qkv<<<1536, 256, 0, stream>>>(xh, wqkvh, cosT, sinT, qhp, khp, vhp);

  vtrans_kernel<<<32 * 64, 256, 0, stream>>>(vhp, vtp);

  attn_kernel<<<32 * 16, 256, 0, stream>>>(qhp, khp, vtp, aohp);

  gemm_out<<<512, 256, 0, stream>>>(aohp, wouth, out);
}